// Round 1
// baseline (427.279 us; speedup 1.0000x reference)
//
#include <hip/hip_runtime.h>

#define NN 32768
#define KK 16
#define DD 6
// State row per node-slot j: 256 B = h fp16[64] | c fp16[64].  Row 0 = zero.
// g is NOT stored: each parent recomputes g = h_child @ U_f via f16 MFMA
// (matrix pipe was 5% utilized; gather fabric BW is the bottleneck, so
// 384 B -> 256 B per child row is a direct -33% on the dominant cost).
// B-fragments (W_w bf16, U_iuo bf16, U_f fp16) are precomputed once by k_prep
// in MFMA B-frag layout: [nt][ks][lane][8], element j = W[k= ks*32+(ln>>4)*8+j][col= nt*16+(ln&15)].

typedef short short8 __attribute__((ext_vector_type(8)));
typedef float floatx4 __attribute__((ext_vector_type(4)));
typedef _Float16 half4v __attribute__((ext_vector_type(4)));
typedef _Float16 half8 __attribute__((ext_vector_type(8)));

__device__ __forceinline__ float sigm(float x) { return 1.0f / (1.0f + __expf(-x)); }
__device__ __forceinline__ float ftanh(float x) {
    float e = __expf(2.0f * x);
    return 1.0f - 2.0f / (e + 1.0f);
}
__device__ __forceinline__ unsigned short f2bf(float x) {   // RNE fp32->bf16
    union { float f; unsigned u; } v; v.f = x;
    unsigned r = v.u + 0x7FFF + ((v.u >> 16) & 1);
    return (unsigned short)(r >> 16);
}
__device__ __forceinline__ float bf2f(unsigned short h) {
    union { unsigned u; float f; } v; v.u = ((unsigned)h) << 16; return v.f;
}

// ---------------------------------------------------------------------------
// K_PREP: build global B-fragments once.  32768 values total, 1 per thread.
//   WwF: 16 nt x 2 ks x 64 ln x 8  bf16   (W_w,  256 cols)
//   BiF: 12 nt x 2 ks x 64 ln x 8  bf16   (U_iuo, 192 cols)
//   BfF:  4 nt x 2 ks x 64 ln x 8  fp16   (U_f,    64 cols)
__global__ __launch_bounds__(256) void k_prep(
    const float* __restrict__ W_w, const float* __restrict__ U_iuo,
    const float* __restrict__ U_f,
    unsigned short* __restrict__ WwF, unsigned short* __restrict__ BiF,
    _Float16* __restrict__ BfF)
{
    const int t = blockIdx.x * 256 + threadIdx.x;      // 0..32767
    if (t < 16384) {
        const int u = t, j = u & 7, ln = (u >> 3) & 63, ks = (u >> 9) & 1, nt = u >> 10;
        const int col = nt * 16 + (ln & 15), k = ks * 32 + (ln >> 4) * 8 + j;
        WwF[u] = f2bf(W_w[k * 256 + col]);
    } else if (t < 28672) {
        const int u = t - 16384, j = u & 7, ln = (u >> 3) & 63, ks = (u >> 9) & 1, nt = u >> 10;
        const int col = nt * 16 + (ln & 15), k = ks * 32 + (ln >> 4) * 8 + j;
        BiF[u] = f2bf(U_iuo[k * 192 + col]);
    } else {
        const int u = t - 28672, j = u & 7, ln = (u >> 3) & 63, ks = (u >> 9) & 1, nt = u >> 10;
        const int col = nt * 16 + (ln & 15), k = ks * 32 + (ln >> 4) * 8 + j;
        BfF[u] = (_Float16)U_f[k * 64 + col];
    }
}

// ---------------------------------------------------------------------------
// K0_ALL: LDS-free, barrier-free.  A-frags converted in-register from direct
// E row loads (lane (lr,qd) owns node wv*16+lr, cols ks*32+qd*8..+8); B-frags
// read from the L1/L2-resident 32 KB WwF table.  Same WxF frag layout as before.
__global__ __launch_bounds__(256) void k0_all(
    const int* __restrict__ labels, const float* __restrict__ E,
    const unsigned short* __restrict__ WwF, const float* __restrict__ W_b,
    _Float16* __restrict__ WxF)
{
    const int tid = threadIdx.x;
    const int blk = blockIdx.x & 511;
    const int dep = blockIdx.x >> 9;
    const int n0 = blk * 64;
    const int ln = tid & 63, wv = tid >> 6;
    const int lr = ln & 15, qd = ln >> 4;
    const int lab = labels[(size_t)dep * NN + n0 + wv * 16 + lr];
    const float4* __restrict__ e4 = (const float4*)(E + (size_t)lab * 64);
    short8 af[2];
#pragma unroll
    for (int ks = 0; ks < 2; ++ks) {
        const float4 v0 = e4[ks * 8 + qd * 2 + 0];
        const float4 v1 = e4[ks * 8 + qd * 2 + 1];
        short8 a;
        a[0] = (short)f2bf(v0.x); a[1] = (short)f2bf(v0.y);
        a[2] = (short)f2bf(v0.z); a[3] = (short)f2bf(v0.w);
        a[4] = (short)f2bf(v1.x); a[5] = (short)f2bf(v1.y);
        a[6] = (short)f2bf(v1.z); a[7] = (short)f2bf(v1.w);
        af[ks] = a;
    }
    const short8* __restrict__ bw = (const short8*)WwF;
    _Float16* __restrict__ base =
        WxF + ((size_t)(dep * 512 + blk) * 4 + wv) * 16 * 256 + (size_t)ln * 4;
#pragma unroll
    for (int nt = 0; nt < 16; ++nt) {
        floatx4 a = (floatx4){0.f, 0.f, 0.f, 0.f};
        a = __builtin_amdgcn_mfma_f32_16x16x32_bf16(af[0], bw[(nt * 2 + 0) * 64 + ln], a, 0, 0, 0);
        a = __builtin_amdgcn_mfma_f32_16x16x32_bf16(af[1], bw[(nt * 2 + 1) * 64 + ln], a, 0, 0, 0);
        const float bb = W_b[nt * 16 + lr];
        half4v hv;
#pragma unroll
        for (int r = 0; r < 4; ++r) hv[r] = (_Float16)(a[r] + bb);
        *(half4v*)&base[nt * 256] = hv;
    }
}

// ---------------------------------------------------------------------------
// KD: 256 B state rows.  Per child k: h gathered in A-frag layout (2 x 16 B),
// g = mfma_f16(h, U_f) per nt tile (C-layout matches wfx/c slots), c gathered
// in C-layout (16 x 2 B).  h_sum accumulates in A-frag registers -> in-register
// split-bf16 -> iuo GEMM with global BiF frags.  No hsum LDS restage, no
// epilogue U_f GEMM, only one barrier (8 KB Bf stage).
__global__ __launch_bounds__(256, 4) void kd_fused(
    const int* __restrict__ cidx, const _Float16* __restrict__ sprev,
    const _Float16* __restrict__ Wx, const unsigned short* __restrict__ BiF,
    const _Float16* __restrict__ BfF, _Float16* __restrict__ snext,
    float* __restrict__ out, int first, int last)
{
    __shared__ __align__(16) _Float16 BfL[4096];       // [4 nt][2 ks][64 ln][8]
    const int tid = threadIdx.x;
    const int n0 = blockIdx.x * 64;
    {   // stage U_f frags: 512 half8, 2 per thread
        const half8* __restrict__ src = (const half8*)BfF;
        half8* dst = (half8*)BfL;
        dst[tid] = src[tid];
        dst[tid + 256] = src[tid + 256];
    }
    const int ln = tid & 63, wv = tid >> 6;
    const int lr = ln & 15, qd = ln >> 4;
    const _Float16* __restrict__ wbase =
        Wx + ((size_t)blockIdx.x * 4 + wv) * 16 * 256 + (size_t)ln * 4;
    __syncthreads();

    float hsA[2][8];
    float bfv[4][4];
#pragma unroll
    for (int ks = 0; ks < 2; ++ks)
#pragma unroll
        for (int j = 0; j < 8; ++j) hsA[ks][j] = 0.f;
#pragma unroll
    for (int r = 0; r < 4; ++r)
#pragma unroll
        for (int nt = 0; nt < 4; ++nt) bfv[r][nt] = 0.f;

    if (!first) {
        float wfx[4][4];
#pragma unroll
        for (int nt = 0; nt < 4; ++nt) {                 // f tiles 0..3 (C-layout)
            const half4v fv = *(const half4v*)&wbase[nt * 256];
#pragma unroll
            for (int r = 0; r < 4; ++r) wfx[r][nt] = (float)fv[r];
        }
        const size_t hb = (size_t)(n0 + wv * 16 + lr) * KK;        // A-frag node row
        const size_t cb = (size_t)(n0 + wv * 16 + qd * 4) * KK;    // C-layout nodes
        const half8* __restrict__ bl = (const half8*)BfL;
        int idh = cidx[hb];
        int idc[4];
#pragma unroll
        for (int r = 0; r < 4; ++r) idc[r] = cidx[cb + r * KK];
#pragma unroll 1
        for (int k = 0; k < KK; ++k) {
            // h of this lane's A-row child: 2 x 16 B (row 0 == zeros for masked)
            const half8 hf0 = *(const half8*)&sprev[(size_t)idh * 128 + qd * 8];
            const half8 hf1 = *(const half8*)&sprev[(size_t)idh * 128 + 32 + qd * 8];
            _Float16 cv[4][4];
#pragma unroll
            for (int r = 0; r < 4; ++r)
#pragma unroll
                for (int nt = 0; nt < 4; ++nt)
                    cv[r][nt] = sprev[(size_t)idc[r] * 128 + 64 + nt * 16 + lr];
            int idhn = 0, idcn[4];
            if (k + 1 < KK) {                            // prefetch ids k+1
                idhn = cidx[hb + k + 1];
#pragma unroll
                for (int r = 0; r < 4; ++r) idcn[r] = cidx[cb + r * KK + k + 1];
            }
            // g tiles = h_k @ U_f (f16 MFMA), then f-gate accumulate in C-layout
#pragma unroll
            for (int nt = 0; nt < 4; ++nt) {
                floatx4 g = (floatx4){0.f, 0.f, 0.f, 0.f};
                g = __builtin_amdgcn_mfma_f32_16x16x32_f16(hf0, bl[(nt * 2 + 0) * 64 + ln], g, 0, 0, 0);
                g = __builtin_amdgcn_mfma_f32_16x16x32_f16(hf1, bl[(nt * 2 + 1) * 64 + ln], g, 0, 0, 0);
#pragma unroll
                for (int r = 0; r < 4; ++r)
                    bfv[r][nt] = fmaf(sigm(wfx[r][nt] + g[r]), (float)cv[r][nt], bfv[r][nt]);
            }
            // h_sum accumulates natively in A-frag position
#pragma unroll
            for (int j = 0; j < 8; ++j) {
                hsA[0][j] += (float)hf0[j];
                hsA[1][j] += (float)hf1[j];
            }
            if (k + 1 < KK) {
                idh = idhn;
#pragma unroll
                for (int r = 0; r < 4; ++r) idc[r] = idcn[r];
            }
        }
    }
    // ---- iuo GEMM: in-register split-bf16 hsum @ U_iuo, 12 out-tiles
    floatx4 acc[12];
#pragma unroll
    for (int nt = 0; nt < 12; ++nt) acc[nt] = (floatx4){0.f, 0.f, 0.f, 0.f};
    if (!first) {
        short8 ahi[2], alo[2];
#pragma unroll
        for (int ks = 0; ks < 2; ++ks)
#pragma unroll
            for (int j = 0; j < 8; ++j) {
                const float v = hsA[ks][j];
                const unsigned short hi = f2bf(v);
                ahi[ks][j] = (short)hi;
                alo[ks][j] = (short)f2bf(v - bf2f(hi));
            }
        const short8* __restrict__ bi = (const short8*)BiF;
#pragma unroll
        for (int nt = 0; nt < 12; ++nt) {
            floatx4 a = (floatx4){0.f, 0.f, 0.f, 0.f};
#pragma unroll
            for (int ks = 0; ks < 2; ++ks) {
                const short8 bu = bi[(nt * 2 + ks) * 64 + ln];
                a = __builtin_amdgcn_mfma_f32_16x16x32_bf16(alo[ks], bu, a, 0, 0, 0);
                a = __builtin_amdgcn_mfma_f32_16x16x32_bf16(ahi[ks], bu, a, 0, 0, 0);
            }
            acc[nt] = a;
        }
    }
    // ---- gate epilogue
#pragma unroll
    for (int nt = 0; nt < 4; ++nt) {
        const int col = nt * 16 + lr;
        const half4v iv = *(const half4v*)&wbase[(4 + nt) * 256];
        const half4v uv = *(const half4v*)&wbase[(8 + nt) * 256];
        const half4v ov = *(const half4v*)&wbase[(12 + nt) * 256];
#pragma unroll
        for (int r = 0; r < 4; ++r) {
            const int node = n0 + wv * 16 + qd * 4 + r;
            const float ig = sigm(acc[nt][r] + (float)iv[r]);
            const float ug = ftanh(acc[4 + nt][r] + (float)uv[r]);
            const float og = sigm(acc[8 + nt][r] + (float)ov[r]);
            const float nc = fmaf(ig, ug, bfv[r][nt]);
            const float nh = og * ftanh(nc);
            if (last) {
                out[(size_t)node * 64 + col] = nh;
            } else {
                snext[(size_t)(node + 1) * 128 + col] = (_Float16)nh;
                snext[(size_t)(node + 1) * 128 + 64 + col] = (_Float16)nc;
            }
        }
    }
    if (!last && blockIdx.x == 0 && tid < 64)
        ((unsigned*)snext)[tid] = 0u;                    // zero init-state row
}

extern "C" void kernel_launch(void* const* d_in, const int* in_sizes, int n_in,
                              void* d_out, int out_size, void* d_ws, size_t ws_size,
                              hipStream_t stream)
{
    const int*   labels = (const int*)d_in[0];    // [6, 32768]
    const int*   child  = (const int*)d_in[1];    // [6, 32768, 16]
    const float* E      = (const float*)d_in[2];  // [100000, 64]
    const float* W_w    = (const float*)d_in[3];  // [64, 256]
    const float* W_b    = (const float*)d_in[4];  // [256]
    const float* U_f    = (const float*)d_in[5];  // [64, 64]
    const float* U_iuo  = (const float*)d_in[6];  // [64, 192]
    float* out = (float*)d_out;

    // ws: s0,s1 = (NN+1)*256 B state ping-pong (8.4 MB each);
    //     WxF = 6 x NN*256 fp16 frags (100.7 MB); then WwF/BiF/BfF frag tables (64 KB).
    _Float16* s0 = (_Float16*)d_ws;
    _Float16* s1 = s0 + (size_t)(NN + 1) * 128;
    _Float16* WxF = s1 + (size_t)(NN + 1) * 128;
    unsigned short* WwF = (unsigned short*)(WxF + (size_t)6 * NN * 256);
    unsigned short* BiF = WwF + 16384;
    _Float16* BfF = (_Float16*)(BiF + 12288);

    k_prep<<<128, 256, 0, stream>>>(W_w, U_iuo, U_f, WwF, BiF, BfF);
    k0_all<<<6 * (NN / 64), 256, 0, stream>>>(labels, E, WwF, W_b, WxF);

    _Float16* sp = s0;
    _Float16* sn = s1;
    for (int d = 0; d < DD; ++d) {
        const int last = (d == DD - 1);
        kd_fused<<<NN / 64, 256, 0, stream>>>(
            child + (size_t)d * NN * KK, sp,
            WxF + (size_t)d * NN * 256,
            BiF, BfF, sn, out, d == 0, last);
        _Float16* ts = sp; sp = sn; sn = ts;
    }
}

// Round 2
// 409.762 us; speedup vs baseline: 1.0427x; 1.0427x over previous
//
#include <hip/hip_runtime.h>

#define NN 32768
#define KK 16
#define DD 6
// State row per node-slot j: 256 B = h fp16[64] (natural col order) | c fp16[64]
// PERMUTED as [lr][nt] (pos = (col&15)*4 + (col>>4)) so a C-layout lane reads its
// 4 c values as one 8B load.  Row 0 = zero.
// g = h @ U_f recomputed per (parent,child) via f16 MFMA (matrix pipe ~idle).
// Gather discipline (round-1 regression fix): per wave-k the FULL 256 B rows of
// 16 children are fetched with 4 coalesced dwordx4 insts (16 rows x 64 B per
// inst = 64 lines/wave-k vs 160 scattered in round 1), staged via wave-private
// LDS (in-order DS pipe, no barrier), re-read as h A-frags + permuted c.
// Children split 8/8 across wave pairs -> grid 1024, 16 waves/CU.

typedef short short8 __attribute__((ext_vector_type(8)));
typedef float floatx4 __attribute__((ext_vector_type(4)));
typedef _Float16 half4v __attribute__((ext_vector_type(4)));
typedef _Float16 half8 __attribute__((ext_vector_type(8)));

__device__ __forceinline__ float sigm(float x) { return 1.0f / (1.0f + __expf(-x)); }
__device__ __forceinline__ float ftanh(float x) {
    float e = __expf(2.0f * x);
    return 1.0f - 2.0f / (e + 1.0f);
}
__device__ __forceinline__ unsigned short f2bf(float x) {   // RNE fp32->bf16
    union { float f; unsigned u; } v; v.f = x;
    unsigned r = v.u + 0x7FFF + ((v.u >> 16) & 1);
    return (unsigned short)(r >> 16);
}
__device__ __forceinline__ float bf2f(unsigned short h) {
    union { unsigned u; float f; } v; v.u = ((unsigned)h) << 16; return v.f;
}

// ---------------------------------------------------------------------------
// K_PREP: build global B-fragments once.  32768 values total, 1 per thread.
//   WwF: 16 nt x 2 ks x 64 ln x 8  bf16   (W_w,  256 cols)
//   BiF: 12 nt x 2 ks x 64 ln x 8  bf16   (U_iuo, 192 cols)
//   BfF:  4 nt x 2 ks x 64 ln x 8  fp16   (U_f,    64 cols)
__global__ __launch_bounds__(256) void k_prep(
    const float* __restrict__ W_w, const float* __restrict__ U_iuo,
    const float* __restrict__ U_f,
    unsigned short* __restrict__ WwF, unsigned short* __restrict__ BiF,
    _Float16* __restrict__ BfF)
{
    const int t = blockIdx.x * 256 + threadIdx.x;      // 0..32767
    if (t < 16384) {
        const int u = t, j = u & 7, ln = (u >> 3) & 63, ks = (u >> 9) & 1, nt = u >> 10;
        const int col = nt * 16 + (ln & 15), k = ks * 32 + (ln >> 4) * 8 + j;
        WwF[u] = f2bf(W_w[k * 256 + col]);
    } else if (t < 28672) {
        const int u = t - 16384, j = u & 7, ln = (u >> 3) & 63, ks = (u >> 9) & 1, nt = u >> 10;
        const int col = nt * 16 + (ln & 15), k = ks * 32 + (ln >> 4) * 8 + j;
        BiF[u] = f2bf(U_iuo[k * 192 + col]);
    } else {
        const int u = t - 28672, j = u & 7, ln = (u >> 3) & 63, ks = (u >> 9) & 1, nt = u >> 10;
        const int col = nt * 16 + (ln & 15), k = ks * 32 + (ln >> 4) * 8 + j;
        BfF[u] = (_Float16)U_f[k * 64 + col];
    }
}

// ---------------------------------------------------------------------------
// K0_ALL: LDS-free, barrier-free (proven ~20us in round 1).  A-frags converted
// in-register from direct E row loads; B-frags from the L2-hot WwF table.
__global__ __launch_bounds__(256) void k0_all(
    const int* __restrict__ labels, const float* __restrict__ E,
    const unsigned short* __restrict__ WwF, const float* __restrict__ W_b,
    _Float16* __restrict__ WxF)
{
    const int tid = threadIdx.x;
    const int blk = blockIdx.x & 511;
    const int dep = blockIdx.x >> 9;
    const int n0 = blk * 64;
    const int ln = tid & 63, wv = tid >> 6;
    const int lr = ln & 15, qd = ln >> 4;
    const int lab = labels[(size_t)dep * NN + n0 + wv * 16 + lr];
    const float4* __restrict__ e4 = (const float4*)(E + (size_t)lab * 64);
    short8 af[2];
#pragma unroll
    for (int ks = 0; ks < 2; ++ks) {
        const float4 v0 = e4[ks * 8 + qd * 2 + 0];
        const float4 v1 = e4[ks * 8 + qd * 2 + 1];
        short8 a;
        a[0] = (short)f2bf(v0.x); a[1] = (short)f2bf(v0.y);
        a[2] = (short)f2bf(v0.z); a[3] = (short)f2bf(v0.w);
        a[4] = (short)f2bf(v1.x); a[5] = (short)f2bf(v1.y);
        a[6] = (short)f2bf(v1.z); a[7] = (short)f2bf(v1.w);
        af[ks] = a;
    }
    const short8* __restrict__ bw = (const short8*)WwF;
    _Float16* __restrict__ base =
        WxF + ((size_t)(dep * 512 + blk) * 4 + wv) * 16 * 256 + (size_t)ln * 4;
#pragma unroll
    for (int nt = 0; nt < 16; ++nt) {
        floatx4 a = (floatx4){0.f, 0.f, 0.f, 0.f};
        a = __builtin_amdgcn_mfma_f32_16x16x32_bf16(af[0], bw[(nt * 2 + 0) * 64 + ln], a, 0, 0, 0);
        a = __builtin_amdgcn_mfma_f32_16x16x32_bf16(af[1], bw[(nt * 2 + 1) * 64 + ln], a, 0, 0, 0);
        const float bb = W_b[nt * 16 + lr];
        half4v hv;
#pragma unroll
        for (int r = 0; r < 4; ++r) hv[r] = (_Float16)(a[r] + bb);
        *(half4v*)&base[nt * 256] = hv;
    }
}

// ---------------------------------------------------------------------------
// KD: block = 32 nodes, 4 waves.  wave wv: group g=wv&1 (16 nodes), k-half
// kh=wv>>1 (children kh*8..+8).  Stage stride 272 B (16 B pad: phase-level
// bank-conflict-free for the b128 A-frag reads).
__global__ __launch_bounds__(256, 4) void kd_fused(
    const int* __restrict__ cidx, const _Float16* __restrict__ sprev,
    const _Float16* __restrict__ Wx, const unsigned short* __restrict__ BiF,
    const _Float16* __restrict__ BfF, _Float16* __restrict__ snext,
    float* __restrict__ out, int first, int last)
{
    __shared__ __align__(16) _Float16 BfL[4096];          // [4 nt][2 ks][64 ln][8]
    __shared__ __align__(16) unsigned char stage[4 * 4352];  // per wave: 16 rows x 272 B
    const int tid = threadIdx.x;
    {   // stage U_f frags: 512 half8, 2 per thread
        const half8* __restrict__ src = (const half8*)BfF;
        half8* dst = (half8*)BfL;
        dst[tid] = src[tid];
        dst[tid + 256] = src[tid + 256];
    }
    const int ln = tid & 63, wv = tid >> 6;
    const int g = wv & 1, kh = wv >> 1;
    const int lr = ln & 15, qd = ln >> 4;
    const int n0 = blockIdx.x * 32;
    unsigned char* const myst = stage + wv * 4352;
    const _Float16* __restrict__ wbase =
        Wx + ((size_t)(blockIdx.x >> 1) * 4 + (blockIdx.x & 1) * 2 + g) * 4096 + (size_t)ln * 4;
    __syncthreads();

    float hsA[2][8];
    float bfv[4][4];
#pragma unroll
    for (int ks = 0; ks < 2; ++ks)
#pragma unroll
        for (int j = 0; j < 8; ++j) hsA[ks][j] = 0.f;
#pragma unroll
    for (int r = 0; r < 4; ++r)
#pragma unroll
        for (int nt = 0; nt < 4; ++nt) bfv[r][nt] = 0.f;

    if (!first) {
        float wfx[4][4];
#pragma unroll
        for (int nt = 0; nt < 4; ++nt) {                  // f tiles 0..3 (C-layout)
            const half4v fv = *(const half4v*)&wbase[nt * 256];
#pragma unroll
            for (int r = 0; r < 4; ++r) wfx[r][nt] = (float)fv[r];
        }
        const int m = ln >> 2, ch = ln & 3;               // gather: lane -> row m, chunk ch
        const size_t ib = (size_t)(n0 + g * 16 + m) * KK + kh * 8;
        const uint4* __restrict__ sp4 = (const uint4*)sprev;
        uint4* const st4 = (uint4*)myst;
        const half8* __restrict__ bl = (const half8*)BfL;
        {   // prologue: rows for kk=0
            const int id = cidx[ib];
            uint4 rb[4];
#pragma unroll
            for (int i = 0; i < 4; ++i) rb[i] = sp4[(size_t)id * 16 + ch + 4 * i];
#pragma unroll
            for (int i = 0; i < 4; ++i) st4[m * 17 + ch + 4 * i] = rb[i];
        }
#pragma unroll 1
        for (int kk = 0; kk < 8; ++kk) {
            uint4 nb[4];
            if (kk < 7) {                                 // T14: issue k+1 loads early
                const int idn = cidx[ib + kk + 1];
#pragma unroll
                for (int i = 0; i < 4; ++i) nb[i] = sp4[(size_t)idn * 16 + ch + 4 * i];
            }
            // h of parent lr's child, A-frag pieces (conflict-free b128)
            const half8 hf0 = *(const half8*)(myst + lr * 272 + qd * 16);
            const half8 hf1 = *(const half8*)(myst + lr * 272 + 64 + qd * 16);
            half4v cq[4];                                  // permuted c: 4 vals contiguous
#pragma unroll
            for (int r = 0; r < 4; ++r)
                cq[r] = *(const half4v*)(myst + (qd * 4 + r) * 272 + 128 + lr * 8);
            // g tiles = h_k @ U_f (f16 MFMA, C-layout), f-gate accumulate
#pragma unroll
            for (int nt = 0; nt < 4; ++nt) {
                floatx4 gg = (floatx4){0.f, 0.f, 0.f, 0.f};
                gg = __builtin_amdgcn_mfma_f32_16x16x32_f16(hf0, bl[(nt * 2 + 0) * 64 + ln], gg, 0, 0, 0);
                gg = __builtin_amdgcn_mfma_f32_16x16x32_f16(hf1, bl[(nt * 2 + 1) * 64 + ln], gg, 0, 0, 0);
#pragma unroll
                for (int r = 0; r < 4; ++r)
                    bfv[r][nt] = fmaf(sigm(wfx[r][nt] + gg[r]), (float)cq[r][nt], bfv[r][nt]);
            }
#pragma unroll
            for (int j = 0; j < 8; ++j) {                 // h_sum in A-frag position
                hsA[0][j] += (float)hf0[j];
                hsA[1][j] += (float)hf1[j];
            }
            if (kk < 7) {                                 // stage k+1 after all reads of k
#pragma unroll
                for (int i = 0; i < 4; ++i) st4[m * 17 + ch + 4 * i] = nb[i];
            }
        }
        // ---- combine k-halves across wave pairs (reuse stage memory)
        __syncthreads();
        float* const pbh = (float*)(stage + g * 4352);
        float* const pbb = (float*)(stage + (2 + g) * 4352);
        if (kh == 1) {
#pragma unroll
            for (int ks = 0; ks < 2; ++ks)
#pragma unroll
                for (int j = 0; j < 8; ++j) pbh[ln * 17 + ks * 8 + j] = hsA[ks][j];
#pragma unroll
            for (int r = 0; r < 4; ++r)
#pragma unroll
                for (int nt = 0; nt < 4; ++nt) pbb[ln * 17 + r * 4 + nt] = bfv[r][nt];
        }
        __syncthreads();
        if (kh == 0) {
#pragma unroll
            for (int ks = 0; ks < 2; ++ks)
#pragma unroll
                for (int j = 0; j < 8; ++j) hsA[ks][j] += pbh[ln * 17 + ks * 8 + j];
#pragma unroll
            for (int r = 0; r < 4; ++r)
#pragma unroll
                for (int nt = 0; nt < 4; ++nt) bfv[r][nt] += pbb[ln * 17 + r * 4 + nt];
        }
    }
    if (kh == 0) {
        // ---- iuo GEMM: in-register split-bf16 hsum @ U_iuo, 12 out-tiles
        floatx4 acc[12];
#pragma unroll
        for (int nt = 0; nt < 12; ++nt) acc[nt] = (floatx4){0.f, 0.f, 0.f, 0.f};
        if (!first) {
            short8 ahi[2], alo[2];
#pragma unroll
            for (int ks = 0; ks < 2; ++ks)
#pragma unroll
                for (int j = 0; j < 8; ++j) {
                    const float v = hsA[ks][j];
                    const unsigned short hi = f2bf(v);
                    ahi[ks][j] = (short)hi;
                    alo[ks][j] = (short)f2bf(v - bf2f(hi));
                }
            const short8* __restrict__ bi = (const short8*)BiF;
#pragma unroll
            for (int nt = 0; nt < 12; ++nt) {
                floatx4 a = (floatx4){0.f, 0.f, 0.f, 0.f};
#pragma unroll
                for (int ks = 0; ks < 2; ++ks) {
                    const short8 bu = bi[(nt * 2 + ks) * 64 + ln];
                    a = __builtin_amdgcn_mfma_f32_16x16x32_bf16(alo[ks], bu, a, 0, 0, 0);
                    a = __builtin_amdgcn_mfma_f32_16x16x32_bf16(ahi[ks], bu, a, 0, 0, 0);
                }
                acc[nt] = a;
            }
        }
        // ---- gate epilogue
#pragma unroll
        for (int nt = 0; nt < 4; ++nt) {
            const half4v iv = *(const half4v*)&wbase[(4 + nt) * 256];
            const half4v uv = *(const half4v*)&wbase[(8 + nt) * 256];
            const half4v ov = *(const half4v*)&wbase[(12 + nt) * 256];
#pragma unroll
            for (int r = 0; r < 4; ++r) {
                const int node = n0 + g * 16 + qd * 4 + r;
                const float ig = sigm(acc[nt][r] + (float)iv[r]);
                const float ug = ftanh(acc[4 + nt][r] + (float)uv[r]);
                const float og = sigm(acc[8 + nt][r] + (float)ov[r]);
                const float nc = fmaf(ig, ug, bfv[r][nt]);
                const float nh = og * ftanh(nc);
                if (last) {
                    out[(size_t)node * 64 + nt * 16 + lr] = nh;
                } else {
                    snext[(size_t)(node + 1) * 128 + nt * 16 + lr] = (_Float16)nh;
                    snext[(size_t)(node + 1) * 128 + 64 + lr * 4 + nt] = (_Float16)nc;
                }
            }
        }
    }
    if (!last && blockIdx.x == 0 && tid < 64)
        ((unsigned*)snext)[tid] = 0u;                     // zero init-state row
}

extern "C" void kernel_launch(void* const* d_in, const int* in_sizes, int n_in,
                              void* d_out, int out_size, void* d_ws, size_t ws_size,
                              hipStream_t stream)
{
    const int*   labels = (const int*)d_in[0];    // [6, 32768]
    const int*   child  = (const int*)d_in[1];    // [6, 32768, 16]
    const float* E      = (const float*)d_in[2];  // [100000, 64]
    const float* W_w    = (const float*)d_in[3];  // [64, 256]
    const float* W_b    = (const float*)d_in[4];  // [256]
    const float* U_f    = (const float*)d_in[5];  // [64, 64]
    const float* U_iuo  = (const float*)d_in[6];  // [64, 192]
    float* out = (float*)d_out;

    // ws: s0,s1 = (NN+1)*256 B state ping-pong (8.4 MB each);
    //     WxF = 6 x NN*256 fp16 frags (100.7 MB); then WwF/BiF/BfF frag tables (64 KB).
    _Float16* s0 = (_Float16*)d_ws;
    _Float16* s1 = s0 + (size_t)(NN + 1) * 128;
    _Float16* WxF = s1 + (size_t)(NN + 1) * 128;
    unsigned short* WwF = (unsigned short*)(WxF + (size_t)6 * NN * 256);
    unsigned short* BiF = WwF + 16384;
    _Float16* BfF = (_Float16*)(BiF + 12288);

    k_prep<<<128, 256, 0, stream>>>(W_w, U_iuo, U_f, WwF, BiF, BfF);
    k0_all<<<6 * (NN / 64), 256, 0, stream>>>(labels, E, WwF, W_b, WxF);

    _Float16* sp = s0;
    _Float16* sn = s1;
    for (int d = 0; d < DD; ++d) {
        const int last = (d == DD - 1);
        kd_fused<<<NN / 32, 256, 0, stream>>>(
            child + (size_t)d * NN * KK, sp,
            WxF + (size_t)d * NN * 256,
            BiF, BfF, sn, out, d == 0, last);
        _Float16* ts = sp; sp = sn; sn = ts;
    }
}

// Round 3
// 405.945 us; speedup vs baseline: 1.0526x; 1.0094x over previous
//
#include <hip/hip_runtime.h>

#define NN 32768
#define KK 16
#define DD 6
// State row per node-slot j: 256 B = h fp16[64] (natural col order) | c fp16[64]
// PERMUTED as [lr][nt] (pos = (col&15)*4 + (col>>4)) so a C-layout lane reads its
// 4 c values as one 8B load.  Row 0 = zero.
// g = h @ U_f recomputed per (parent,child) via f16 MFMA (matrix pipe ~idle).
// Gather: per wave-k the FULL 256 B rows of 16 children are fetched with 4
// coalesced dwordx4 insts (16 rows x 64 B per inst), staged via wave-private
// LDS, re-read as h A-frags + permuted c.  Children split 8/8 across wave pairs.
// Round-3 fix: state WRITES are assembled as full 256 B row images in the
// wave-private LDS stage and copied out with 4 x dwordx4 per lane (1 KB
// contiguous per inst, full lines) -- round-2's scattered 2 B stores inflated
// WRITE_SIZE to 121 MB (vs 8.4 MB legit) via partial-sector writebacks.

typedef short short8 __attribute__((ext_vector_type(8)));
typedef float floatx4 __attribute__((ext_vector_type(4)));
typedef _Float16 half4v __attribute__((ext_vector_type(4)));
typedef _Float16 half8 __attribute__((ext_vector_type(8)));

__device__ __forceinline__ float sigm(float x) { return 1.0f / (1.0f + __expf(-x)); }
__device__ __forceinline__ float ftanh(float x) {
    float e = __expf(2.0f * x);
    return 1.0f - 2.0f / (e + 1.0f);
}
__device__ __forceinline__ unsigned short f2bf(float x) {   // RNE fp32->bf16
    union { float f; unsigned u; } v; v.f = x;
    unsigned r = v.u + 0x7FFF + ((v.u >> 16) & 1);
    return (unsigned short)(r >> 16);
}
__device__ __forceinline__ float bf2f(unsigned short h) {
    union { unsigned u; float f; } v; v.u = ((unsigned)h) << 16; return v.f;
}

// ---------------------------------------------------------------------------
// K_PREP: build global B-fragments once.  32768 values total, 1 per thread.
//   WwF: 16 nt x 2 ks x 64 ln x 8  bf16   (W_w,  256 cols)
//   BiF: 12 nt x 2 ks x 64 ln x 8  bf16   (U_iuo, 192 cols)
//   BfF:  4 nt x 2 ks x 64 ln x 8  fp16   (U_f,    64 cols)
__global__ __launch_bounds__(256) void k_prep(
    const float* __restrict__ W_w, const float* __restrict__ U_iuo,
    const float* __restrict__ U_f,
    unsigned short* __restrict__ WwF, unsigned short* __restrict__ BiF,
    _Float16* __restrict__ BfF)
{
    const int t = blockIdx.x * 256 + threadIdx.x;      // 0..32767
    if (t < 16384) {
        const int u = t, j = u & 7, ln = (u >> 3) & 63, ks = (u >> 9) & 1, nt = u >> 10;
        const int col = nt * 16 + (ln & 15), k = ks * 32 + (ln >> 4) * 8 + j;
        WwF[u] = f2bf(W_w[k * 256 + col]);
    } else if (t < 28672) {
        const int u = t - 16384, j = u & 7, ln = (u >> 3) & 63, ks = (u >> 9) & 1, nt = u >> 10;
        const int col = nt * 16 + (ln & 15), k = ks * 32 + (ln >> 4) * 8 + j;
        BiF[u] = f2bf(U_iuo[k * 192 + col]);
    } else {
        const int u = t - 28672, j = u & 7, ln = (u >> 3) & 63, ks = (u >> 9) & 1, nt = u >> 10;
        const int col = nt * 16 + (ln & 15), k = ks * 32 + (ln >> 4) * 8 + j;
        BfF[u] = (_Float16)U_f[k * 64 + col];
    }
}

// ---------------------------------------------------------------------------
// K0_ALL: LDS-free, barrier-free.  A-frags converted in-register from direct
// E row loads; B-frags from the L2-hot WwF table.
__global__ __launch_bounds__(256) void k0_all(
    const int* __restrict__ labels, const float* __restrict__ E,
    const unsigned short* __restrict__ WwF, const float* __restrict__ W_b,
    _Float16* __restrict__ WxF)
{
    const int tid = threadIdx.x;
    const int blk = blockIdx.x & 511;
    const int dep = blockIdx.x >> 9;
    const int n0 = blk * 64;
    const int ln = tid & 63, wv = tid >> 6;
    const int lr = ln & 15, qd = ln >> 4;
    const int lab = labels[(size_t)dep * NN + n0 + wv * 16 + lr];
    const float4* __restrict__ e4 = (const float4*)(E + (size_t)lab * 64);
    short8 af[2];
#pragma unroll
    for (int ks = 0; ks < 2; ++ks) {
        const float4 v0 = e4[ks * 8 + qd * 2 + 0];
        const float4 v1 = e4[ks * 8 + qd * 2 + 1];
        short8 a;
        a[0] = (short)f2bf(v0.x); a[1] = (short)f2bf(v0.y);
        a[2] = (short)f2bf(v0.z); a[3] = (short)f2bf(v0.w);
        a[4] = (short)f2bf(v1.x); a[5] = (short)f2bf(v1.y);
        a[6] = (short)f2bf(v1.z); a[7] = (short)f2bf(v1.w);
        af[ks] = a;
    }
    const short8* __restrict__ bw = (const short8*)WwF;
    _Float16* __restrict__ base =
        WxF + ((size_t)(dep * 512 + blk) * 4 + wv) * 16 * 256 + (size_t)ln * 4;
#pragma unroll
    for (int nt = 0; nt < 16; ++nt) {
        floatx4 a = (floatx4){0.f, 0.f, 0.f, 0.f};
        a = __builtin_amdgcn_mfma_f32_16x16x32_bf16(af[0], bw[(nt * 2 + 0) * 64 + ln], a, 0, 0, 0);
        a = __builtin_amdgcn_mfma_f32_16x16x32_bf16(af[1], bw[(nt * 2 + 1) * 64 + ln], a, 0, 0, 0);
        const float bb = W_b[nt * 16 + lr];
        half4v hv;
#pragma unroll
        for (int r = 0; r < 4; ++r) hv[r] = (_Float16)(a[r] + bb);
        *(half4v*)&base[nt * 256] = hv;
    }
}

// ---------------------------------------------------------------------------
// KD: block = 32 nodes, 4 waves.  wave wv: group g=wv&1 (16 nodes), k-half
// kh=wv>>1 (children kh*8..+8).  Stage stride 272 B (phase-conflict-free
// b128 A-frag reads).  Epilogue: row images assembled in myst (256 B stride)
// and written with full-line dwordx4 copies.
__global__ __launch_bounds__(256, 4) void kd_fused(
    const int* __restrict__ cidx, const _Float16* __restrict__ sprev,
    const _Float16* __restrict__ Wx, const unsigned short* __restrict__ BiF,
    const _Float16* __restrict__ BfF, _Float16* __restrict__ snext,
    float* __restrict__ out, int first, int last)
{
    __shared__ __align__(16) _Float16 BfL[4096];          // [4 nt][2 ks][64 ln][8]
    __shared__ __align__(16) unsigned char stage[4 * 4352];  // per wave: 16 rows x 272 B
    const int tid = threadIdx.x;
    {   // stage U_f frags: 512 half8, 2 per thread
        const half8* __restrict__ src = (const half8*)BfF;
        half8* dst = (half8*)BfL;
        dst[tid] = src[tid];
        dst[tid + 256] = src[tid + 256];
    }
    const int ln = tid & 63, wv = tid >> 6;
    const int g = wv & 1, kh = wv >> 1;
    const int lr = ln & 15, qd = ln >> 4;
    const int n0 = blockIdx.x * 32;
    unsigned char* const myst = stage + wv * 4352;
    const _Float16* __restrict__ wbase =
        Wx + ((size_t)(blockIdx.x >> 1) * 4 + (blockIdx.x & 1) * 2 + g) * 4096 + (size_t)ln * 4;
    __syncthreads();

    float hsA[2][8];
    float bfv[4][4];
#pragma unroll
    for (int ks = 0; ks < 2; ++ks)
#pragma unroll
        for (int j = 0; j < 8; ++j) hsA[ks][j] = 0.f;
#pragma unroll
    for (int r = 0; r < 4; ++r)
#pragma unroll
        for (int nt = 0; nt < 4; ++nt) bfv[r][nt] = 0.f;

    if (!first) {
        float wfx[4][4];
#pragma unroll
        for (int nt = 0; nt < 4; ++nt) {                  // f tiles 0..3 (C-layout)
            const half4v fv = *(const half4v*)&wbase[nt * 256];
#pragma unroll
            for (int r = 0; r < 4; ++r) wfx[r][nt] = (float)fv[r];
        }
        const int m = ln >> 2, ch = ln & 3;               // gather: lane -> row m, chunk ch
        const size_t ib = (size_t)(n0 + g * 16 + m) * KK + kh * 8;
        const uint4* __restrict__ sp4 = (const uint4*)sprev;
        uint4* const st4 = (uint4*)myst;
        const half8* __restrict__ bl = (const half8*)BfL;
        {   // prologue: rows for kk=0
            const int id = cidx[ib];
            uint4 rb[4];
#pragma unroll
            for (int i = 0; i < 4; ++i) rb[i] = sp4[(size_t)id * 16 + ch + 4 * i];
#pragma unroll
            for (int i = 0; i < 4; ++i) st4[m * 17 + ch + 4 * i] = rb[i];
        }
#pragma unroll 1
        for (int kk = 0; kk < 8; ++kk) {
            uint4 nb[4];
            if (kk < 7) {                                 // T14: issue k+1 loads early
                const int idn = cidx[ib + kk + 1];
#pragma unroll
                for (int i = 0; i < 4; ++i) nb[i] = sp4[(size_t)idn * 16 + ch + 4 * i];
            }
            // h of parent lr's child, A-frag pieces (conflict-free b128)
            const half8 hf0 = *(const half8*)(myst + lr * 272 + qd * 16);
            const half8 hf1 = *(const half8*)(myst + lr * 272 + 64 + qd * 16);
            half4v cq[4];                                  // permuted c: 4 vals contiguous
#pragma unroll
            for (int r = 0; r < 4; ++r)
                cq[r] = *(const half4v*)(myst + (qd * 4 + r) * 272 + 128 + lr * 8);
            // g tiles = h_k @ U_f (f16 MFMA, C-layout), f-gate accumulate
#pragma unroll
            for (int nt = 0; nt < 4; ++nt) {
                floatx4 gg = (floatx4){0.f, 0.f, 0.f, 0.f};
                gg = __builtin_amdgcn_mfma_f32_16x16x32_f16(hf0, bl[(nt * 2 + 0) * 64 + ln], gg, 0, 0, 0);
                gg = __builtin_amdgcn_mfma_f32_16x16x32_f16(hf1, bl[(nt * 2 + 1) * 64 + ln], gg, 0, 0, 0);
#pragma unroll
                for (int r = 0; r < 4; ++r)
                    bfv[r][nt] = fmaf(sigm(wfx[r][nt] + gg[r]), (float)cq[r][nt], bfv[r][nt]);
            }
#pragma unroll
            for (int j = 0; j < 8; ++j) {                 // h_sum in A-frag position
                hsA[0][j] += (float)hf0[j];
                hsA[1][j] += (float)hf1[j];
            }
            if (kk < 7) {                                 // stage k+1 after all reads of k
#pragma unroll
                for (int i = 0; i < 4; ++i) st4[m * 17 + ch + 4 * i] = nb[i];
            }
        }
        // ---- combine k-halves across wave pairs (reuse stage memory)
        __syncthreads();
        float* const pbh = (float*)(stage + g * 4352);
        float* const pbb = (float*)(stage + (2 + g) * 4352);
        if (kh == 1) {
#pragma unroll
            for (int ks = 0; ks < 2; ++ks)
#pragma unroll
                for (int j = 0; j < 8; ++j) pbh[ln * 17 + ks * 8 + j] = hsA[ks][j];
#pragma unroll
            for (int r = 0; r < 4; ++r)
#pragma unroll
                for (int nt = 0; nt < 4; ++nt) pbb[ln * 17 + r * 4 + nt] = bfv[r][nt];
        }
        __syncthreads();
        if (kh == 0) {
#pragma unroll
            for (int ks = 0; ks < 2; ++ks)
#pragma unroll
                for (int j = 0; j < 8; ++j) hsA[ks][j] += pbh[ln * 17 + ks * 8 + j];
#pragma unroll
            for (int r = 0; r < 4; ++r)
#pragma unroll
                for (int nt = 0; nt < 4; ++nt) bfv[r][nt] += pbb[ln * 17 + r * 4 + nt];
        }
    }
    if (kh == 0) {
        // ---- iuo GEMM: in-register split-bf16 hsum @ U_iuo, 12 out-tiles
        floatx4 acc[12];
#pragma unroll
        for (int nt = 0; nt < 12; ++nt) acc[nt] = (floatx4){0.f, 0.f, 0.f, 0.f};
        if (!first) {
            short8 ahi[2], alo[2];
#pragma unroll
            for (int ks = 0; ks < 2; ++ks)
#pragma unroll
                for (int j = 0; j < 8; ++j) {
                    const float v = hsA[ks][j];
                    const unsigned short hi = f2bf(v);
                    ahi[ks][j] = (short)hi;
                    alo[ks][j] = (short)f2bf(v - bf2f(hi));
                }
            const short8* __restrict__ bi = (const short8*)BiF;
#pragma unroll
            for (int nt = 0; nt < 12; ++nt) {
                floatx4 a = (floatx4){0.f, 0.f, 0.f, 0.f};
#pragma unroll
                for (int ks = 0; ks < 2; ++ks) {
                    const short8 bu = bi[(nt * 2 + ks) * 64 + ln];
                    a = __builtin_amdgcn_mfma_f32_16x16x32_bf16(alo[ks], bu, a, 0, 0, 0);
                    a = __builtin_amdgcn_mfma_f32_16x16x32_bf16(ahi[ks], bu, a, 0, 0, 0);
                }
                acc[nt] = a;
            }
        }
        // ---- gate epilogue: assemble 256 B row images in wave-private LDS
        _Float16* const rb = (_Float16*)myst;              // [16 rows][128 halves]
#pragma unroll
        for (int nt = 0; nt < 4; ++nt) {
            const half4v iv = *(const half4v*)&wbase[(4 + nt) * 256];
            const half4v uv = *(const half4v*)&wbase[(8 + nt) * 256];
            const half4v ov = *(const half4v*)&wbase[(12 + nt) * 256];
#pragma unroll
            for (int r = 0; r < 4; ++r) {
                const int mrow = qd * 4 + r;
                const float ig = sigm(acc[nt][r] + (float)iv[r]);
                const float ug = ftanh(acc[4 + nt][r] + (float)uv[r]);
                const float og = sigm(acc[8 + nt][r] + (float)ov[r]);
                const float nc = fmaf(ig, ug, bfv[r][nt]);
                const float nh = og * ftanh(nc);
                if (last) {
                    out[(size_t)(n0 + g * 16 + mrow) * 64 + nt * 16 + lr] = nh;
                } else {
                    rb[mrow * 128 + nt * 16 + lr] = (_Float16)nh;       // h natural
                    rb[mrow * 128 + 64 + lr * 4 + nt] = (_Float16)nc;   // c permuted
                }
            }
        }
        if (!last) {
            // full-line copy: 16 rows x 256 B contiguous (rows n0+g*16+1 ..)
            const uint4* const s4 = (const uint4*)myst;
            uint4* const d4 = (uint4*)((char*)snext + (size_t)(n0 + g * 16 + 1) * 256);
#pragma unroll
            for (int i = 0; i < 4; ++i) d4[ln + i * 64] = s4[ln + i * 64];
        }
    }
    if (!last && blockIdx.x == 0 && tid < 64)
        ((unsigned*)snext)[tid] = 0u;                     // zero init-state row
}

extern "C" void kernel_launch(void* const* d_in, const int* in_sizes, int n_in,
                              void* d_out, int out_size, void* d_ws, size_t ws_size,
                              hipStream_t stream)
{
    const int*   labels = (const int*)d_in[0];    // [6, 32768]
    const int*   child  = (const int*)d_in[1];    // [6, 32768, 16]
    const float* E      = (const float*)d_in[2];  // [100000, 64]
    const float* W_w    = (const float*)d_in[3];  // [64, 256]
    const float* W_b    = (const float*)d_in[4];  // [256]
    const float* U_f    = (const float*)d_in[5];  // [64, 64]
    const float* U_iuo  = (const float*)d_in[6];  // [64, 192]
    float* out = (float*)d_out;

    // ws: s0,s1 = (NN+1)*256 B state ping-pong (8.4 MB each);
    //     WxF = 6 x NN*256 fp16 frags (100.7 MB); then WwF/BiF/BfF frag tables (64 KB).
    _Float16* s0 = (_Float16*)d_ws;
    _Float16* s1 = s0 + (size_t)(NN + 1) * 128;
    _Float16* WxF = s1 + (size_t)(NN + 1) * 128;
    unsigned short* WwF = (unsigned short*)(WxF + (size_t)6 * NN * 256);
    unsigned short* BiF = WwF + 16384;
    _Float16* BfF = (_Float16*)(BiF + 12288);

    k_prep<<<128, 256, 0, stream>>>(W_w, U_iuo, U_f, WwF, BiF, BfF);
    k0_all<<<6 * (NN / 64), 256, 0, stream>>>(labels, E, WwF, W_b, WxF);

    _Float16* sp = s0;
    _Float16* sn = s1;
    for (int d = 0; d < DD; ++d) {
        const int last = (d == DD - 1);
        kd_fused<<<NN / 32, 256, 0, stream>>>(
            child + (size_t)d * NN * KK, sp,
            WxF + (size_t)d * NN * 256,
            BiF, BfF, sn, out, d == 0, last);
        _Float16* ts = sp; sp = sn; sn = ts;
    }
}